// Round 18
// baseline (369.937 us; speedup 1.0000x reference)
//
#include <hip/hip_runtime.h>
#include <math.h>

#define EPSF 1e-5f

typedef short bf16x8 __attribute__((ext_vector_type(8)));
typedef float f32x4 __attribute__((ext_vector_type(4)));

static __device__ __forceinline__ unsigned short f2bf(float x) {
  unsigned u = __float_as_uint(x);
  unsigned r = (u + 0x7FFFu + ((u >> 16) & 1u)) >> 16;
  return (unsigned short)r;
}

static __device__ __forceinline__ float msgv(float F, float S) {
  float sig = __builtin_amdgcn_rcpf(1.0f + __expf(-F));
  float sp = fmaxf(S, 0.f) + __logf(1.0f + __expf(-fabsf(S)));
  return sig * sp;
}

// async global->LDS, 16B/lane; LDS dest = wave-uniform base + lane*16.
static __device__ __forceinline__ void gload16(const void* g, void* l) {
  __builtin_amdgcn_global_load_lds(
      (const __attribute__((address_space(1))) unsigned int*)g,
      (__attribute__((address_space(3))) unsigned int*)l, 16, 0, 0);
}

// ---------------- Prep (fused): cvt_x | bpack_edge(K=96) | bpack_node | hist --
// Edge B rows kk=0..95: kk<32 -> W[128+kk] (eattr); kk>=32 -> W[32+kk] (x_src).
// Node B rows kk=0..63 -> W[kk] (x_dst).
__global__ __launch_bounds__(256) void prep_kernel(
    const float* __restrict__ x, const float* __restrict__ Wf,
    const float* __restrict__ Ws, const int* __restrict__ ei,
    unsigned short* __restrict__ xbf, unsigned short* __restrict__ Bfrag,
    unsigned short* __restrict__ Bfrag2, int* __restrict__ deg, int NCV,
    int total8, int E) {
  const int b = blockIdx.x, t = threadIdx.x;
  if (b < NCV) {
    int i = b * 256 + t;
    if (i < total8) {
      float4 a = ((const float4*)x)[i * 2];
      float4 c = ((const float4*)x)[i * 2 + 1];
      unsigned short o[8];
      o[0] = f2bf(a.x); o[1] = f2bf(a.y); o[2] = f2bf(a.z); o[3] = f2bf(a.w);
      o[4] = f2bf(c.x); o[5] = f2bf(c.y); o[6] = f2bf(c.z); o[7] = f2bf(c.w);
      ((uint4*)xbf)[i] = *(uint4*)o;
    }
  } else if (b < NCV + 6) {
    int g2 = (b - NCV) * 256 + t;
    if (g2 < 1536) {
      const int ks = g2 >> 9, t8 = (g2 >> 6) & 7, l = g2 & 63;
      const int q = l & 15, g = l >> 4;
      const float* W = (t8 < 4) ? Wf : Ws;
      const int col = (t8 & 3) * 16 + q;
      unsigned short out[8];
#pragma unroll
      for (int i = 0; i < 8; ++i) {
        int kk = ks * 32 + g * 8 + i;
        int wr = (kk < 32) ? (128 + kk) : (32 + kk);
        out[i] = f2bf(W[(size_t)wr * 64 + col]);
      }
      *(uint4*)&Bfrag[((size_t)(ks * 8 + t8) * 64 + l) * 8] = *(uint4*)out;
    }
  } else if (b < NCV + 10) {
    int g2 = (b - NCV - 6) * 256 + t;
    if (g2 < 1024) {
      const int ks = g2 >> 9, t8 = (g2 >> 6) & 7, l = g2 & 63;
      const int q = l & 15, g = l >> 4;
      const float* W = (t8 < 4) ? Wf : Ws;
      const int col = (t8 & 3) * 16 + q;
      unsigned short out[8];
#pragma unroll
      for (int i = 0; i < 8; ++i) {
        int kk = ks * 32 + g * 8 + i;
        out[i] = f2bf(W[(size_t)kk * 64 + col]);
      }
      *(uint4*)&Bfrag2[((size_t)(ks * 8 + t8) * 64 + l) * 8] = *(uint4*)out;
    }
  } else {
    int i = (b - NCV - 10) * 256 + t;
    if (i < E) atomicAdd(&deg[ei[E + i]], 1);
  }
}

// ---------------- K1: Pd2[n][f] = (x@Wf_i + bf, x@Ws_i + bs) fp32 ------------
__global__ __launch_bounds__(256, 4) void node_mfma(
    const unsigned short* __restrict__ xbf,
    const unsigned short* __restrict__ Bfrag2, const float* __restrict__ bf_,
    const float* __restrict__ bs_, float2* __restrict__ Pd2, int N) {
  __shared__ __align__(16) short Bsh[16][64][8];  // 16 KB
  for (int i = threadIdx.x; i < 1024; i += 256)
    ((uint4*)Bsh)[i] = ((const uint4*)Bfrag2)[i];
  __syncthreads();
  const int lane = threadIdx.x & 63, w = threadIdx.x >> 6;
  const int q = lane & 15, g = lane >> 4;
  const int row0 = blockIdx.x * 64;
  const float bfv = bf_[w * 16 + q], bsv = bs_[w * 16 + q];
  f32x4 accf[4], accs[4];
#pragma unroll
  for (int mt = 0; mt < 4; ++mt) {
    accf[mt] = (f32x4){0.f, 0.f, 0.f, 0.f};
    accs[mt] = (f32x4){0.f, 0.f, 0.f, 0.f};
  }
#pragma unroll
  for (int ks = 0; ks < 2; ++ks) {
    const bf16x8 Bfr = *(const bf16x8*)&Bsh[ks * 8 + w][lane][0];
    const bf16x8 Bsr = *(const bf16x8*)&Bsh[ks * 8 + 4 + w][lane][0];
#pragma unroll
    for (int mt = 0; mt < 4; ++mt) {
      int row = min(row0 + mt * 16 + q, N - 1);
      const bf16x8 a = *(const bf16x8*)(xbf + (size_t)row * 64 + ks * 32 + g * 8);
      accf[mt] = __builtin_amdgcn_mfma_f32_16x16x32_bf16(a, Bfr, accf[mt], 0, 0, 0);
      accs[mt] = __builtin_amdgcn_mfma_f32_16x16x32_bf16(a, Bsr, accs[mt], 0, 0, 0);
    }
  }
#pragma unroll
  for (int mt = 0; mt < 4; ++mt) {
#pragma unroll
    for (int r = 0; r < 4; ++r) {
      int row = row0 + mt * 16 + g * 4 + r;
      if (row < N)
        Pd2[(size_t)row * 64 + w * 16 + q] =
            make_float2(accf[mt][r] + bfv, accs[mt][r] + bsv);
    }
  }
}

// ---------------- CSR build: scan over TILE counts (tcnt = ceil(deg/16)) ----
__global__ __launch_bounds__(256) void scan_a(const int* __restrict__ deg,
                                              int* __restrict__ bsum, int N) {
  const int idx = blockIdx.x * 256 + threadIdx.x;
  int v = (idx < N) ? ((deg[idx] + 15) >> 4) : 0;
#pragma unroll
  for (int o = 32; o > 0; o >>= 1) v += __shfl_down(v, o);
  __shared__ int ws4[4];
  if ((threadIdx.x & 63) == 0) ws4[threadIdx.x >> 6] = v;
  __syncthreads();
  if (threadIdx.x == 0) bsum[blockIdx.x] = ws4[0] + ws4[1] + ws4[2] + ws4[3];
}

__global__ __launch_bounds__(256) void scan_b(const int* __restrict__ bsum,
                                              int* __restrict__ bpre,
                                              int* __restrict__ tile_total,
                                              int NB) {
  const int t = threadIdx.x;
  const int lane = t & 63, w = t >> 6;
  int v = (t < NB) ? bsum[t] : 0;
  int sc = v;
#pragma unroll
  for (int o = 1; o < 64; o <<= 1) {
    int u = __shfl_up(sc, o);
    if (lane >= o) sc += u;
  }
  __shared__ int wsum[4];
  if (lane == 63) wsum[w] = sc;
  __syncthreads();
  int add = 0;
#pragma unroll
  for (int k = 0; k < 4; ++k) add += (k < w) ? wsum[k] : 0;
  bpre[t] = (sc - v) + add;
  if (t == 255) tile_total[0] = sc + add;
}

__global__ __launch_bounds__(256) void scan_c(const int* __restrict__ deg,
                                              const int* __restrict__ bpre,
                                              int* __restrict__ cursor,
                                              int* __restrict__ tstart, int N) {
  const int t = threadIdx.x;
  const int lane = t & 63, w = t >> 6;
  const int idx = blockIdx.x * 256 + t;
  int d = (idx < N) ? ((deg[idx] + 15) >> 4) : 0;
  int sc = d;
#pragma unroll
  for (int o = 1; o < 64; o <<= 1) {
    int u = __shfl_up(sc, o);
    if (lane >= o) sc += u;
  }
  __shared__ int wsum[4];
  if (lane == 63) wsum[w] = sc;
  __syncthreads();
  int add = bpre[blockIdx.x];
#pragma unroll
  for (int k = 0; k < 4; ++k) add += (k < w) ? wsum[k] : 0;
  if (idx < N) {
    int ts = add + (sc - d);
    tstart[idx] = ts;
    cursor[idx] = ts * 16;
  }
}

// ---------------- CSR build: scatter into padded single-dst tiles ------------
__global__ __launch_bounds__(256) void scatter_pack(
    const int* __restrict__ ei, int* __restrict__ cursor,
    const int* __restrict__ deg, const int* __restrict__ tstart,
    const float* __restrict__ eattr, int* __restrict__ epk,
    int* __restrict__ thdr, unsigned short* __restrict__ eabf, int E) {
  int i = blockIdx.x * 256 + threadIdx.x;
  if (i >= E) return;
  const int src = ei[i];
  const int dst = ei[E + i];
  const int pos = atomicAdd(&cursor[dst], 1);
  epk[pos] = (src & 0xFFFF) | (dst << 16);
  const int ts = tstart[dst];
  const int k = pos - ts * 16;
  if ((k & 15) == 0) {
    int vc = min(16, deg[dst] - (k & ~15));
    thdr[ts + (k >> 4)] = dst | (vc << 16);
  }
  const float4* er = (const float4*)(eattr + (size_t)i * 32);
  unsigned short o[32];
#pragma unroll
  for (int kk = 0; kk < 8; ++kk) {
    float4 v = er[kk];
    o[kk * 4] = f2bf(v.x); o[kk * 4 + 1] = f2bf(v.y);
    o[kk * 4 + 2] = f2bf(v.z); o[kk * 4 + 3] = f2bf(v.w);
  }
  uint4* dp = (uint4*)(eabf + (size_t)pos * 32);
#pragma unroll
  for (int kk = 0; kk < 4; ++kk) dp[kk] = ((uint4*)o)[kk];
}

// ---------------- K2: persistent edge kernel, K=96 + wave-uniform Pd ---------
// Single-dst 16-edge tiles; one WAVE per run; PRIVATE 2x3KB LDS dbuf; B(96x128)
// in 24KB block LDS (48KB total -> 3 blocks/CU, 3 waves/SIMD). Fixed VMEM/iter:
// 3 stage gload + 4 Pd reg-loads + 2 prefetch + 1 atomic -> vmcnt(15) never
// drains atomics. Epilogue: Pd add + masked msgv + butterfly + ONE wave atomic.
__global__ __launch_bounds__(256) void edge_fused(
    const int* __restrict__ epk, const int* __restrict__ thdr,
    const unsigned short* __restrict__ eabf,
    const unsigned short* __restrict__ xbf,
    const unsigned short* __restrict__ Bfrag, const float2* __restrict__ Pd2,
    float* __restrict__ agg, const int* __restrict__ tile_total, int N) {
  __shared__ __align__(16) unsigned char Bls[24576];
  __shared__ __align__(16) unsigned char AshA[24576];  // 4 waves * 2 * 3072

  for (int i = threadIdx.x; i < 1536; i += 256)
    ((uint4*)Bls)[i] = ((const uint4*)Bfrag)[i];
  __syncthreads();

  const int lane = threadIdx.x & 63, w = threadIdx.x >> 6;
  const int q = lane & 15, g = lane >> 4;
  const int row = lane >> 2, c = lane & 3;
  const int cs = c ^ ((row >> 1) & 3);  // source-side swizzle

  const int T = tile_total[0];
  const int nB = gridDim.x;  // 768
  const int cb = (blockIdx.x & 7) * (nB >> 3) + (blockIdx.x >> 3);
  const int qT = T / nB, rT = T - qT * nB;
  const int bt0 = cb * qT + min(cb, rT);
  const int bt1 = bt0 + qT + (cb < rT ? 1 : 0);
  const int blen = bt1 - bt0;
  const int per = (blen + 3) >> 2;
  const int wt0 = bt0 + w * per;
  const int wt1 = min(bt1, wt0 + per);
  if (wt0 >= wt1) return;
  const int tlast = wt1 - 1;

  char* myA = (char*)AshA + w * 6144;

  // Stage one tile: 3 gload_lds (eattr slab + 2 x_src slabs) + 4 Pd reg-loads.
  auto STAGE = [&](int bufSel, int tile, int er, int hdr, float2 (&pd)[4]) {
    unsigned su = (unsigned)(er & 0xFFFF);
    if (su >= (unsigned)N) su = 0;
    unsigned du = (unsigned)(hdr & 0xFFFF);
    if (du >= (unsigned)N) du = 0;
    char* base = myA + bufSel * 3072;
    gload16(eabf + ((size_t)tile * 16 + row) * 32 + cs * 8, base);
    gload16(xbf + (size_t)su * 64 + cs * 8, base + 1024);
    gload16(xbf + (size_t)su * 64 + 32 + cs * 8, base + 2048);
#pragma unroll
    for (int nt = 0; nt < 4; ++nt) pd[nt] = Pd2[(size_t)du * 64 + nt * 16 + q];
  };

  // ---- prologue (dummy atomic normalizes the per-iter VMEM count) ----
  atomicAdd(&agg[lane], 0.0f);
  int tcur = wt0;
  int hdr_cur = thdr[tcur];
  int ep_c = epk[(size_t)tcur * 16 + row];
  float2 pd_cur[4], pd_nxt[4];
  STAGE(0, tcur, ep_c, hdr_cur, pd_cur);
  const int t1i = min(tcur + 1, tlast);
  int ep_n = epk[(size_t)t1i * 16 + row];
  int hdr_n = thdr[t1i];
  int buf = 0;

  for (;;) {
    const int tn = min(tcur + 1, tlast);
    const int t2i = min(tcur + 2, tlast);
    STAGE(buf ^ 1, tn, ep_n, hdr_n, pd_nxt);     // 3 gload + 4 Pd
    int ep_nn = epk[(size_t)t2i * 16 + row];     // 1
    int hdr_nn = thdr[t2i];                      // 1
    __builtin_amdgcn_sched_barrier(0);
    asm volatile("s_waitcnt vmcnt(15)" ::: "memory");
    __builtin_amdgcn_sched_barrier(0);

    // ---- MFMA over buf: 3 K-slabs x 4 col-tiles x {f,s} ----
    const char* Ab = myA + buf * 3072;
    f32x4 accf[4], accs[4];
#pragma unroll
    for (int nt = 0; nt < 4; ++nt) {
      accf[nt] = (f32x4){0.f, 0.f, 0.f, 0.f};
      accs[nt] = (f32x4){0.f, 0.f, 0.f, 0.f};
    }
#pragma unroll
    for (int ks = 0; ks < 3; ++ks) {
      const bf16x8 a =
          *(const bf16x8*)(Ab + ks * 1024 + q * 64 + ((g ^ ((q >> 1) & 3)) << 4));
#pragma unroll
      for (int nt = 0; nt < 4; ++nt) {
        const bf16x8 Bfr =
            *(const bf16x8*)(Bls + (((ks * 8 + nt) * 64 + lane) << 4));
        const bf16x8 Bsr =
            *(const bf16x8*)(Bls + (((ks * 8 + 4 + nt) * 64 + lane) << 4));
        accf[nt] =
            __builtin_amdgcn_mfma_f32_16x16x32_bf16(a, Bfr, accf[nt], 0, 0, 0);
        accs[nt] =
            __builtin_amdgcn_mfma_f32_16x16x32_bf16(a, Bsr, accs[nt], 0, 0, 0);
      }
    }

    // ---- epilogue: Pd add, masked msgv, butterfly, ONE wave atomic ----
    const int dstT = hdr_cur & 0xFFFF;
    const int vcnt = hdr_cur >> 16;
    float tot0, tot1, tot2, tot3;
#pragma unroll
    for (int cg = 0; cg < 4; ++cg) {
      float s = 0.f;
#pragma unroll
      for (int r = 0; r < 4; ++r) {
        float m = msgv(accf[cg][r] + pd_cur[cg].x, accs[cg][r] + pd_cur[cg].y);
        s += (g * 4 + r < vcnt) ? m : 0.f;
      }
      s += __shfl_xor(s, 16);
      s += __shfl_xor(s, 32);
      if (cg == 0) tot0 = s;
      else if (cg == 1) tot1 = s;
      else if (cg == 2) tot2 = s;
      else tot3 = s;
    }
    float v = (g == 0) ? tot0 : (g == 1) ? tot1 : (g == 2) ? tot2 : tot3;
    unsigned dd = (unsigned)dstT;
    float vv = (dd < (unsigned)N) ? v : 0.f;
    dd = min(dd, (unsigned)(N - 1));
    atomicAdd(&agg[(size_t)dd * 64 + g * 16 + q], vv);  // 1

    if (tcur == tlast) break;
    tcur += 1;
    buf ^= 1;
    hdr_cur = hdr_n;
    hdr_n = hdr_nn;
    ep_n = ep_nn;
#pragma unroll
    for (int nt = 0; nt < 4; ++nt) pd_cur[nt] = pd_nxt[nt];
  }
}

// ---------------- K3: per-feature reductions over agg and x ----------------
__global__ __launch_bounds__(256) void stats_kernel(
    const float* __restrict__ agg, const float* __restrict__ x,
    float* __restrict__ stats, int N) {
  const int f = threadIdx.x & 63;
  const int sub = threadIdx.x >> 6;
  float sa = 0, sa2 = 0, sx = 0, sx2 = 0, sax = 0;
  for (int r = blockIdx.x * 4 + sub; r < N; r += gridDim.x * 4) {
    float a = agg[(size_t)r * 64 + f];
    float xv = x[(size_t)r * 64 + f];
    sa += a; sa2 += a * a; sx += xv; sx2 += xv * xv; sax += a * xv;
  }
  __shared__ float lds[4][5][64];
  lds[sub][0][f] = sa; lds[sub][1][f] = sa2; lds[sub][2][f] = sx;
  lds[sub][3][f] = sx2; lds[sub][4][f] = sax;
  __syncthreads();
  if (sub == 0) {
#pragma unroll
    for (int i = 0; i < 5; ++i) {
      float v = lds[0][i][f] + lds[1][i][f] + lds[2][i][f] + lds[3][i][f];
      atomicAdd(&stats[i * 64 + f], v);
    }
  }
}

// ---------------- K5: finalize + BN+res+LN+softplus + pooling ----------------
__global__ __launch_bounds__(256) void node_finish(
    const float* __restrict__ stats, const float* __restrict__ bn_w,
    const float* __restrict__ bn_b, const float* __restrict__ agg,
    const float* __restrict__ x, const int* __restrict__ batch,
    const float* __restrict__ ln_w, const float* __restrict__ ln_b,
    float* __restrict__ add_pool, float* __restrict__ counts, int N,
    int chunk) {
  const int f = threadIdx.x & 63;
  const int sub = threadIdx.x >> 6;
  const float Nf = (float)N;
  const float invN = 1.0f / Nf;
  float Sa = stats[f], Sa2 = stats[64 + f], Sx = stats[128 + f],
        Sx2 = stats[192 + f], Sax = stats[256 + f];
  float mu = Sa * invN;
  float var = Sa2 * invN - mu * mu;
  const float alpha = bn_w[f] / sqrtf(var + EPSF);
  const float beta = bn_b[f] - mu * alpha;
  float Sh = alpha * Sa + Nf * beta + Sx;
  float Sh2 = alpha * alpha * Sa2 + Sx2 + Nf * beta * beta +
              2.f * alpha * Sax + 2.f * alpha * beta * Sa + 2.f * beta * Sx;
#pragma unroll
  for (int o = 32; o > 0; o >>= 1) {
    Sh += __shfl_xor(Sh, o);
    Sh2 += __shfl_xor(Sh2, o);
  }
  const float cnt = Nf * 64.0f;
  const float mean = Sh / cnt;
  const float msq = Sh2 / cnt - mean * mean;
  const float rden = 1.0f / (sqrtf(fmaxf(msq, 0.f)) + EPSF);
  const float lw = ln_w[f] * rden;
  const float lb = ln_b[f];

  const int r0 = blockIdx.x * chunk;
  const int r1 = min(N, r0 + chunk);
  float acc = 0.f, cacc = 0.f;
  int curg = -1;
  for (int r = r0 + sub; r < r1; r += 4) {
    int g = batch[r];
    if (g != curg) {
      if (curg >= 0) {
        atomicAdd(&add_pool[(size_t)curg * 64 + f], acc);
        if (f == 0) atomicAdd(&counts[curg], cacc);
      }
      curg = g; acc = 0.f; cacc = 0.f;
    }
    float h = fmaf(alpha, agg[(size_t)r * 64 + f], beta) + x[(size_t)r * 64 + f];
    float v = (h - mean) * lw + lb;
    float sp = fmaxf(v, 0.f) + __logf(1.0f + __expf(-fabsf(v)));
    acc += sp; cacc += 1.f;
  }
  if (curg >= 0) {
    atomicAdd(&add_pool[(size_t)curg * 64 + f], acc);
    if (f == 0) atomicAdd(&counts[curg], cacc);
  }
}

// ---------------- K6: graph head (vectorized) ----------------
__global__ __launch_bounds__(1024) void graph_out(
    const float* __restrict__ add_pool, const float* __restrict__ counts,
    const float* __restrict__ Wl, const float* __restrict__ bl,
    const float* __restrict__ w4, const float* __restrict__ b4,
    float* __restrict__ out, int G) {
  const int t = threadIdx.x;
  const int g = t >> 1, c = t & 1;
  float cnt = fmaxf(counts[g], 1.0f);
  float inv = 1.0f / cnt;
  const float4* ap4 = (const float4*)(add_pool + (size_t)g * 64);
  const float4* W4 = (const float4*)Wl;
  float v = bl[c];
#pragma unroll 4
  for (int k4 = 0; k4 < 16; ++k4) {
    float4 a4 = ap4[k4];
    float4 wa = W4[k4 * 2];
    float4 wb = W4[k4 * 2 + 1];
    float4 wc = W4[32 + k4 * 2];
    float4 wd = W4[32 + k4 * 2 + 1];
    float m0 = c ? wa.y : wa.x, m1 = c ? wa.w : wa.z;
    float m2 = c ? wb.y : wb.x, m3 = c ? wb.w : wb.z;
    float a0 = c ? wc.y : wc.x, a1 = c ? wc.w : wc.z;
    float a2 = c ? wd.y : wd.x, a3 = c ? wd.w : wd.z;
    v = fmaf(a4.x, fmaf(m0, inv, a0), v);
    v = fmaf(a4.y, fmaf(m1, inv, a1), v);
    v = fmaf(a4.z, fmaf(m2, inv, a2), v);
    v = fmaf(a4.w, fmaf(m3, inv, a3), v);
  }

  __shared__ float red[16];
  __shared__ float bc[2];
  float sum = v;
#pragma unroll
  for (int o = 32; o > 0; o >>= 1) sum += __shfl_down(sum, o);
  if ((t & 63) == 0) red[t >> 6] = sum;
  __syncthreads();
  if (t == 0) {
    float tot = 0;
#pragma unroll
    for (int i = 0; i < 16; ++i) tot += red[i];
    bc[0] = tot * (1.0f / 1024.0f);
  }
  __syncthreads();
  const float mean = bc[0];
  const float xc = v - mean;
  float sq = xc * xc;
  __syncthreads();
#pragma unroll
  for (int o = 32; o > 0; o >>= 1) sq += __shfl_down(sq, o);
  if ((t & 63) == 0) red[t >> 6] = sq;
  __syncthreads();
  if (t == 0) {
    float tot = 0;
#pragma unroll
    for (int i = 0; i < 16; ++i) tot += red[i];
    bc[1] = 1.0f / (sqrtf(tot * (1.0f / 1024.0f)) + EPSF);
  }
  __syncthreads();
  out[t] = xc * bc[1] * w4[c] + b4[c];
}

extern "C" void kernel_launch(void* const* d_in, const int* in_sizes, int n_in,
                              void* d_out, int out_size, void* d_ws,
                              size_t ws_size, hipStream_t stream) {
  const float* x = (const float*)d_in[0];
  const int* ei = (const int*)d_in[1];
  const float* eattr = (const float*)d_in[2];
  const int* batch = (const int*)d_in[3];
  const float* Wf = (const float*)d_in[4];
  const float* bf = (const float*)d_in[5];
  const float* Ws = (const float*)d_in[6];
  const float* bs = (const float*)d_in[7];
  const float* bn_w = (const float*)d_in[8];
  const float* bn_b = (const float*)d_in[9];
  const float* ln_w = (const float*)d_in[10];
  const float* ln_b = (const float*)d_in[11];
  const float* Wl = (const float*)d_in[12];
  const float* bl = (const float*)d_in[13];
  const float* w4 = (const float*)d_in[14];
  const float* b4 = (const float*)d_in[15];

  const int N = in_sizes[0] / 64;
  const int E = in_sizes[2] / 32;
  const int G = 512;
  const int NB = (N + 255) / 256;
  const int NCV = (N * 8 + 255) / 256;
  const int NH = (E + 255) / 256;
  const int Tcap = N + (E + 15) / 16;

  // Workspace layout (floats; each chunk multiple of 4 => 16B alignment).
  float* ws = (float*)d_ws;
  float* agg = ws;                                   // N*64  [zeroed]
  float* stats = agg + (size_t)N * 64;               // 320   [zeroed]
  float* add_pool = stats + 320;                     // G*64  [zeroed]
  float* counts = add_pool + (size_t)G * 64;         // G     [zeroed]
  int* deg = (int*)(counts + G);                     // N     [zeroed]
  int* cursor = deg + N;                             // N
  int* tstart = cursor + N;                          // N
  int* tile_total = tstart + N;                      // 4
  int* bsum = tile_total + 4;                        // 256
  int* bpre = bsum + 256;                            // 256
  unsigned short* Bfrag = (unsigned short*)(bpre + 256);   // 12288 ush (24KB)
  unsigned short* Bfrag2 = Bfrag + 12288;                  // 8192 ush (16KB)
  unsigned short* xbf = Bfrag2 + 8192;                     // N*64 ush
  float2* Pd2 = (float2*)(xbf + (size_t)N * 64);           // N*64 float2
  int* thdr = (int*)(Pd2 + (size_t)N * 64);                // Tcap
  int* epk = thdr + Tcap;                                  // Tcap*16 [zeroed]
  unsigned short* eabf = (unsigned short*)(epk + (size_t)Tcap * 16);  // Tcap*512

  size_t zeroFloats = (size_t)N * 64 + 320 + (size_t)G * 64 + G + N;
  hipMemsetAsync(agg, 0, zeroFloats * sizeof(float), stream);
  hipMemsetAsync(epk, 0, (size_t)Tcap * 16 * sizeof(int), stream);

  prep_kernel<<<NCV + 10 + NH, 256, 0, stream>>>(x, Wf, Ws, ei, xbf, Bfrag,
                                                 Bfrag2, deg, NCV, N * 8, E);
  node_mfma<<<(N + 63) / 64, 256, 0, stream>>>(xbf, Bfrag2, bf, bs, Pd2, N);
  scan_a<<<NB, 256, 0, stream>>>(deg, bsum, N);
  scan_b<<<1, 256, 0, stream>>>(bsum, bpre, tile_total, NB);
  scan_c<<<NB, 256, 0, stream>>>(deg, bpre, cursor, tstart, N);
  scatter_pack<<<NH, 256, 0, stream>>>(ei, cursor, deg, tstart, eattr, epk,
                                       thdr, eabf, E);
  edge_fused<<<768, 256, 0, stream>>>(epk, thdr, eabf, xbf, Bfrag, Pd2, agg,
                                      tile_total, N);
  stats_kernel<<<512, 256, 0, stream>>>(agg, x, stats, N);
  const int chunk = (N + 511) / 512;
  node_finish<<<512, 256, 0, stream>>>(stats, bn_w, bn_b, agg, x, batch, ln_w,
                                       ln_b, add_pool, counts, N, chunk);
  graph_out<<<1, 1024, 0, stream>>>(add_pool, counts, Wl, bl, w4, b4,
                                    (float*)d_out, G);
}

// Round 19
// 302.948 us; speedup vs baseline: 1.2211x; 1.2211x over previous
//
#include <hip/hip_runtime.h>
#include <math.h>

#define EPSF 1e-5f

typedef short bf16x8 __attribute__((ext_vector_type(8)));
typedef float f32x4 __attribute__((ext_vector_type(4)));

static __device__ __forceinline__ unsigned short f2bf(float x) {
  unsigned u = __float_as_uint(x);
  unsigned r = (u + 0x7FFFu + ((u >> 16) & 1u)) >> 16;
  return (unsigned short)r;
}

static __device__ __forceinline__ float msgv(float F, float S) {
  float sig = __builtin_amdgcn_rcpf(1.0f + __expf(-F));
  float sp = fmaxf(S, 0.f) + __logf(1.0f + __expf(-fabsf(S)));
  return sig * sp;
}

// async global->LDS, 16B/lane; LDS dest = wave-uniform base + lane*16.
static __device__ __forceinline__ void gload16(const void* g, void* l) {
  __builtin_amdgcn_global_load_lds(
      (const __attribute__((address_space(1))) unsigned int*)g,
      (__attribute__((address_space(3))) unsigned int*)l, 16, 0, 0);
}

// ---------------- Prep (fused): cvt_x | bpack(K=160) | hist ----------------
// B row space kk=0..159: kk<32 -> W[128+kk] (eattr); 32..95 -> W[kk-32]
// (x_dst); 96..159 -> W[kk-32] (x_src). lane l holds
// B[k=(l>>4)*8+i][col=(t8&3)*16+(l&15)], t8<4 => Wf else Ws.
__global__ __launch_bounds__(256) void prep_kernel(
    const float* __restrict__ x, const float* __restrict__ Wf,
    const float* __restrict__ Ws, const int* __restrict__ ei,
    unsigned short* __restrict__ xbf, unsigned short* __restrict__ Bfrag,
    int* __restrict__ deg, int NCV, int total8, int E) {
  const int b = blockIdx.x, t = threadIdx.x;
  if (b < NCV) {
    int i = b * 256 + t;
    if (i < total8) {
      float4 a = ((const float4*)x)[i * 2];
      float4 c = ((const float4*)x)[i * 2 + 1];
      unsigned short o[8];
      o[0] = f2bf(a.x); o[1] = f2bf(a.y); o[2] = f2bf(a.z); o[3] = f2bf(a.w);
      o[4] = f2bf(c.x); o[5] = f2bf(c.y); o[6] = f2bf(c.z); o[7] = f2bf(c.w);
      ((uint4*)xbf)[i] = *(uint4*)o;
    }
  } else if (b < NCV + 10) {
    int g2 = (b - NCV) * 256 + t;
    if (g2 < 2560) {
      const int ks = g2 >> 9, t8 = (g2 >> 6) & 7, l = g2 & 63;
      const int q = l & 15, g = l >> 4;
      const float* W = (t8 < 4) ? Wf : Ws;
      const int col = (t8 & 3) * 16 + q;
      unsigned short out[8];
#pragma unroll
      for (int i = 0; i < 8; ++i) {
        int kk = ks * 32 + g * 8 + i;
        int wr = (kk < 32) ? (128 + kk) : (kk - 32);
        out[i] = f2bf(W[(size_t)wr * 64 + col]);
      }
      *(uint4*)&Bfrag[((size_t)(ks * 8 + t8) * 64 + l) * 8] = *(uint4*)out;
    }
  } else {
    int i = (b - NCV - 10) * 256 + t;
    if (i < E) atomicAdd(&deg[ei[E + i]], 1);
  }
}

// ---------------- CSR build: 3-phase parallel exclusive scan ----------------
__global__ __launch_bounds__(256) void scan_a(const int* __restrict__ deg,
                                              int* __restrict__ bsum, int N) {
  const int idx = blockIdx.x * 256 + threadIdx.x;
  int v = (idx < N) ? deg[idx] : 0;
#pragma unroll
  for (int o = 32; o > 0; o >>= 1) v += __shfl_down(v, o);
  __shared__ int ws4[4];
  if ((threadIdx.x & 63) == 0) ws4[threadIdx.x >> 6] = v;
  __syncthreads();
  if (threadIdx.x == 0) bsum[blockIdx.x] = ws4[0] + ws4[1] + ws4[2] + ws4[3];
}

__global__ __launch_bounds__(256) void scan_b(const int* __restrict__ bsum,
                                              int* __restrict__ bpre, int NB) {
  const int t = threadIdx.x;
  const int lane = t & 63, w = t >> 6;
  int v = (t < NB) ? bsum[t] : 0;
  int sc = v;
#pragma unroll
  for (int o = 1; o < 64; o <<= 1) {
    int u = __shfl_up(sc, o);
    if (lane >= o) sc += u;
  }
  __shared__ int wsum[4];
  if (lane == 63) wsum[w] = sc;
  __syncthreads();
  int add = 0;
#pragma unroll
  for (int k = 0; k < 4; ++k) add += (k < w) ? wsum[k] : 0;
  bpre[t] = (sc - v) + add;
}

__global__ __launch_bounds__(256) void scan_c(const int* __restrict__ deg,
                                              const int* __restrict__ bpre,
                                              int* __restrict__ cursor, int N) {
  const int t = threadIdx.x;
  const int lane = t & 63, w = t >> 6;
  const int idx = blockIdx.x * 256 + t;
  int d = (idx < N) ? deg[idx] : 0;
  int sc = d;
#pragma unroll
  for (int o = 1; o < 64; o <<= 1) {
    int u = __shfl_up(sc, o);
    if (lane >= o) sc += u;
  }
  __shared__ int wsum[4];
  if (lane == 63) wsum[w] = sc;
  __syncthreads();
  int add = bpre[blockIdx.x];
#pragma unroll
  for (int k = 0; k < 4; ++k) add += (k < w) ? wsum[k] : 0;
  if (idx < N) cursor[idx] = add + (sc - d);
}

// ---------------- CSR build: scatter (eid, src|dst<<16) ---------------------
__global__ void scatter_kernel(const int* __restrict__ ei,
                               int* __restrict__ cursor,
                               int2* __restrict__ epk, int E) {
  int i = blockIdx.x * 256 + threadIdx.x;
  if (i >= E) return;
  int dst = ei[E + i];
  int pos = atomicAdd(&cursor[dst], 1);
  epk[pos] = make_int2(i, (ei[i] & 0xFFFF) | (dst << 16));
}

// ---------------- K2: persistent barrier-free edge kernel -------------------
// One WAVE owns a contiguous run of 16-edge tiles with a PRIVATE 2x5KB LDS
// double-buffer (no __syncthreads in loop; wave-private slabs). B(160x128)
// in 40KB block LDS, read per-MFMA (lane-linear ds_read_b128, conflict-free).
// Pipeline: issue stage(t+1) [4 gload_lds + 2 eattr loads] + 2 prefetches =
// 8 VMEM, then vmcnt(8)+lgkmcnt(0) (drains stage(t)+old atomics, keeps
// stage(t+1) in flight) -> MFMA(t) -> eattr ds_write(t+1) -> epilogue(t).
__global__ __launch_bounds__(256) void edge_fused(
    const int2* __restrict__ epk, const float* __restrict__ eattr,
    const unsigned short* __restrict__ xbf,
    const unsigned short* __restrict__ Bfrag, const float* __restrict__ bf_,
    const float* __restrict__ bs_, float* __restrict__ agg, int T16, int N,
    int E) {
  __shared__ __align__(16) unsigned char Bls[40960];
  __shared__ __align__(16) unsigned char AshA[40960];  // 4 waves * 2 * 5120

  for (int i = threadIdx.x; i < 2560; i += 256)
    ((uint4*)Bls)[i] = ((const uint4*)Bfrag)[i];
  __syncthreads();  // once per block (B staging)

  const int lane = threadIdx.x & 63, w = threadIdx.x >> 6;
  const int q = lane & 15, g = lane >> 4;
  const int row = lane >> 2, c = lane & 3;
  const int cs = c ^ ((row >> 1) & 3);  // source-side swizzle

  // XCD-chunked block tile range; contiguous quarter per wave.
  const int nB = gridDim.x;  // 512
  const int cb = (blockIdx.x & 7) * (nB >> 3) + (blockIdx.x >> 3);
  const int qT = T16 / nB, rT = T16 - qT * nB;
  const int bt0 = cb * qT + min(cb, rT);
  const int bt1 = bt0 + qT + (cb < rT ? 1 : 0);
  const int blen = bt1 - bt0;
  const int per = (blen + 3) >> 2;
  const int wt0 = bt0 + w * per;
  const int wt1 = min(bt1, wt0 + per);
  if (wt0 >= wt1) return;
  const int tlast = wt1 - 1;

  float bfv[4], bsv[4];
#pragma unroll
  for (int cg = 0; cg < 4; ++cg) {
    bfv[cg] = bf_[cg * 16 + q];
    bsv[cg] = bs_[cg * 16 + q];
  }

  char* myA = (char*)AshA + w * 10240;

  // Issue stage loads for a tile into buffer bufSel. eattr values returned
  // in registers (converted+written to LDS later, after the MFMA phase).
  auto STAGE_LOADS = [&](int bufSel, int2 er, float4& e0, float4& e1) {
    unsigned eid = ((unsigned)er.x < (unsigned)E) ? (unsigned)er.x : 0u;
    unsigned sv = (unsigned)er.y;
    unsigned su = sv & 0xFFFFu;
    if (su >= (unsigned)N) su = 0;
    unsigned du = sv >> 16;
    if (du >= (unsigned)N) du = 0;
    char* base = myA + bufSel * 5120;
    gload16(xbf + (size_t)du * 64 + cs * 8, base + 1024);
    gload16(xbf + (size_t)du * 64 + 32 + cs * 8, base + 2048);
    gload16(xbf + (size_t)su * 64 + cs * 8, base + 3072);
    gload16(xbf + (size_t)su * 64 + 32 + cs * 8, base + 4096);
    const float* ep_ = eattr + (size_t)eid * 32 + cs * 8;
    e0 = *(const float4*)ep_;
    e1 = *(const float4*)(ep_ + 4);
  };
  auto EATTR_WRITE = [&](int bufSel, float4 e0, float4 e1) {
    bf16x8 sv;
    sv[0] = (short)f2bf(e0.x); sv[1] = (short)f2bf(e0.y);
    sv[2] = (short)f2bf(e0.z); sv[3] = (short)f2bf(e0.w);
    sv[4] = (short)f2bf(e1.x); sv[5] = (short)f2bf(e1.y);
    sv[6] = (short)f2bf(e1.z); sv[7] = (short)f2bf(e1.w);
    *(bf16x8*)(myA + bufSel * 5120 + row * 64 + c * 16) = sv;
  };

  // ---- prologue ----
  int tcur = wt0;
  int2 eprow = epk[(size_t)tcur * 16 + row];
  int2 epq = epk[(size_t)tcur * 16 + q];
  float4 a0, a1;
  STAGE_LOADS(0, eprow, a0, a1);
  const int t1i = min(tcur + 1, tlast);
  int2 eprow_n = epk[(size_t)t1i * 16 + row];
  int2 epq_n = epk[(size_t)t1i * 16 + q];
  EATTR_WRITE(0, a0, a1);
  int buf = 0;

  for (;;) {
    // (a) stage next tile (6 VMEM) + prefetch t+2 views (2 VMEM)
    const int t2i = min(tcur + 2, tlast);
    float4 b0, b1;
    STAGE_LOADS(buf ^ 1, eprow_n, b0, b1);
    int2 eprow_nn = epk[(size_t)t2i * 16 + row];
    int2 epq_nn = epk[(size_t)t2i * 16 + q];
    // (b) counted wait: keep the 8 newest in flight, drain everything older
    __builtin_amdgcn_sched_barrier(0);
    asm volatile("s_waitcnt vmcnt(8)" ::: "memory");
    asm volatile("s_waitcnt lgkmcnt(0)" ::: "memory");
    __builtin_amdgcn_sched_barrier(0);

    // (d) MFMA over buf: 5 K-slabs x 4 col-tiles x {f,s}
    const char* Ab = myA + buf * 5120;
    f32x4 accf[4], accs[4];
#pragma unroll
    for (int nt = 0; nt < 4; ++nt) {
      accf[nt] = (f32x4){0.f, 0.f, 0.f, 0.f};
      accs[nt] = (f32x4){0.f, 0.f, 0.f, 0.f};
    }
#pragma unroll
    for (int ks = 0; ks < 5; ++ks) {
      const bf16x8 a =
          *(const bf16x8*)(Ab + ks * 1024 + q * 64 + ((g ^ ((q >> 1) & 3)) << 4));
#pragma unroll
      for (int nt = 0; nt < 4; ++nt) {
        const bf16x8 Bfr =
            *(const bf16x8*)(Bls + (((ks * 8 + nt) * 64 + lane) << 4));
        const bf16x8 Bsr =
            *(const bf16x8*)(Bls + (((ks * 8 + 4 + nt) * 64 + lane) << 4));
        accf[nt] =
            __builtin_amdgcn_mfma_f32_16x16x32_bf16(a, Bfr, accf[nt], 0, 0, 0);
        accs[nt] =
            __builtin_amdgcn_mfma_f32_16x16x32_bf16(a, Bsr, accs[nt], 0, 0, 0);
      }
    }

    // eattr of next tile: loads landed long ago; convert + ds_write
    EATTR_WRITE(buf ^ 1, b0, b1);

    // (e) epilogue: run-compressed atomics from shfl'd dsts
    const unsigned dA = ((unsigned)__shfl(epq.y, 0)) >> 16;
    const unsigned dB = ((unsigned)__shfl(epq.y, 15)) >> 16;
    if (dA == dB) {
      float tot0, tot1, tot2, tot3;
#pragma unroll
      for (int cg = 0; cg < 4; ++cg) {
        float s = msgv(accf[cg][0] + bfv[cg], accs[cg][0] + bsv[cg]) +
                  msgv(accf[cg][1] + bfv[cg], accs[cg][1] + bsv[cg]) +
                  msgv(accf[cg][2] + bfv[cg], accs[cg][2] + bsv[cg]) +
                  msgv(accf[cg][3] + bfv[cg], accs[cg][3] + bsv[cg]);
        s += __shfl_xor(s, 16);
        s += __shfl_xor(s, 32);
        if (cg == 0) tot0 = s;
        else if (cg == 1) tot1 = s;
        else if (cg == 2) tot2 = s;
        else tot3 = s;
      }
      float v = (g == 0) ? tot0 : (g == 1) ? tot1 : (g == 2) ? tot2 : tot3;
      if (dA < (unsigned)N) atomicAdd(&agg[(size_t)dA * 64 + g * 16 + q], v);
    } else {
      const unsigned d0 = ((unsigned)__shfl(epq.y, g * 4)) >> 16;
      const unsigned d1 = ((unsigned)__shfl(epq.y, g * 4 + 1)) >> 16;
      const unsigned d2 = ((unsigned)__shfl(epq.y, g * 4 + 2)) >> 16;
      const unsigned d3 = ((unsigned)__shfl(epq.y, g * 4 + 3)) >> 16;
#pragma unroll
      for (int cg = 0; cg < 4; ++cg) {
        const int feat = cg * 16 + q;
        unsigned dc = d0;
        float a_ = msgv(accf[cg][0] + bfv[cg], accs[cg][0] + bsv[cg]);
#define STEP(DR, RIDX)                                                        \
  {                                                                           \
    unsigned dr = (DR);                                                       \
    if (dr != dc) {                                                           \
      if (dc < (unsigned)N) atomicAdd(&agg[(size_t)dc * 64 + feat], a_);      \
      dc = dr;                                                                \
      a_ = 0.f;                                                               \
    }                                                                         \
    a_ += msgv(accf[cg][RIDX] + bfv[cg], accs[cg][RIDX] + bsv[cg]);           \
  }
        STEP(d1, 1)
        STEP(d2, 2)
        STEP(d3, 3)
#undef STEP
        if (dc < (unsigned)N) atomicAdd(&agg[(size_t)dc * 64 + feat], a_);
      }
    }

    if (tcur == tlast) break;
    tcur += 1;
    eprow_n = eprow_nn;
    epq = epq_n;
    epq_n = epq_nn;
    buf ^= 1;
  }
}

// ---------------- K3: per-feature reductions over agg and x ----------------
__global__ __launch_bounds__(256) void stats_kernel(
    const float* __restrict__ agg, const float* __restrict__ x,
    float* __restrict__ stats, int N) {
  const int f = threadIdx.x & 63;
  const int sub = threadIdx.x >> 6;
  float sa = 0, sa2 = 0, sx = 0, sx2 = 0, sax = 0;
  for (int r = blockIdx.x * 4 + sub; r < N; r += gridDim.x * 4) {
    float a = agg[(size_t)r * 64 + f];
    float xv = x[(size_t)r * 64 + f];
    sa += a; sa2 += a * a; sx += xv; sx2 += xv * xv; sax += a * xv;
  }
  __shared__ float lds[4][5][64];
  lds[sub][0][f] = sa; lds[sub][1][f] = sa2; lds[sub][2][f] = sx;
  lds[sub][3][f] = sx2; lds[sub][4][f] = sax;
  __syncthreads();
  if (sub == 0) {
#pragma unroll
    for (int i = 0; i < 5; ++i) {
      float v = lds[0][i][f] + lds[1][i][f] + lds[2][i][f] + lds[3][i][f];
      atomicAdd(&stats[i * 64 + f], v);
    }
  }
}

// ---------------- K5: finalize + BN+res+LN+softplus + pooling ----------------
__global__ __launch_bounds__(256) void node_finish(
    const float* __restrict__ stats, const float* __restrict__ bn_w,
    const float* __restrict__ bn_b, const float* __restrict__ agg,
    const float* __restrict__ x, const int* __restrict__ batch,
    const float* __restrict__ ln_w, const float* __restrict__ ln_b,
    float* __restrict__ add_pool, float* __restrict__ counts, int N,
    int chunk) {
  const int f = threadIdx.x & 63;
  const int sub = threadIdx.x >> 6;
  const float Nf = (float)N;
  const float invN = 1.0f / Nf;
  float Sa = stats[f], Sa2 = stats[64 + f], Sx = stats[128 + f],
        Sx2 = stats[192 + f], Sax = stats[256 + f];
  float mu = Sa * invN;
  float var = Sa2 * invN - mu * mu;
  const float alpha = bn_w[f] / sqrtf(var + EPSF);
  const float beta = bn_b[f] - mu * alpha;
  float Sh = alpha * Sa + Nf * beta + Sx;
  float Sh2 = alpha * alpha * Sa2 + Sx2 + Nf * beta * beta +
              2.f * alpha * Sax + 2.f * alpha * beta * Sa + 2.f * beta * Sx;
#pragma unroll
  for (int o = 32; o > 0; o >>= 1) {
    Sh += __shfl_xor(Sh, o);
    Sh2 += __shfl_xor(Sh2, o);
  }
  const float cnt = Nf * 64.0f;
  const float mean = Sh / cnt;
  const float msq = Sh2 / cnt - mean * mean;
  const float rden = 1.0f / (sqrtf(fmaxf(msq, 0.f)) + EPSF);
  const float lw = ln_w[f] * rden;
  const float lb = ln_b[f];

  const int r0 = blockIdx.x * chunk;
  const int r1 = min(N, r0 + chunk);
  float acc = 0.f, cacc = 0.f;
  int curg = -1;
  for (int r = r0 + sub; r < r1; r += 4) {
    int g = batch[r];
    if (g != curg) {
      if (curg >= 0) {
        atomicAdd(&add_pool[(size_t)curg * 64 + f], acc);
        if (f == 0) atomicAdd(&counts[curg], cacc);
      }
      curg = g; acc = 0.f; cacc = 0.f;
    }
    float h = fmaf(alpha, agg[(size_t)r * 64 + f], beta) + x[(size_t)r * 64 + f];
    float v = (h - mean) * lw + lb;
    float sp = fmaxf(v, 0.f) + __logf(1.0f + __expf(-fabsf(v)));
    acc += sp; cacc += 1.f;
  }
  if (curg >= 0) {
    atomicAdd(&add_pool[(size_t)curg * 64 + f], acc);
    if (f == 0) atomicAdd(&counts[curg], cacc);
  }
}

// ---------------- K6: graph head (vectorized) ----------------
__global__ __launch_bounds__(1024) void graph_out(
    const float* __restrict__ add_pool, const float* __restrict__ counts,
    const float* __restrict__ Wl, const float* __restrict__ bl,
    const float* __restrict__ w4, const float* __restrict__ b4,
    float* __restrict__ out, int G) {
  const int t = threadIdx.x;
  const int g = t >> 1, c = t & 1;
  float cnt = fmaxf(counts[g], 1.0f);
  float inv = 1.0f / cnt;
  const float4* ap4 = (const float4*)(add_pool + (size_t)g * 64);
  const float4* W4 = (const float4*)Wl;
  float v = bl[c];
#pragma unroll 4
  for (int k4 = 0; k4 < 16; ++k4) {
    float4 a4 = ap4[k4];
    float4 wa = W4[k4 * 2];
    float4 wb = W4[k4 * 2 + 1];
    float4 wc = W4[32 + k4 * 2];
    float4 wd = W4[32 + k4 * 2 + 1];
    float m0 = c ? wa.y : wa.x, m1 = c ? wa.w : wa.z;
    float m2 = c ? wb.y : wb.x, m3 = c ? wb.w : wb.z;
    float a0 = c ? wc.y : wc.x, a1 = c ? wc.w : wc.z;
    float a2 = c ? wd.y : wd.x, a3 = c ? wd.w : wd.z;
    v = fmaf(a4.x, fmaf(m0, inv, a0), v);
    v = fmaf(a4.y, fmaf(m1, inv, a1), v);
    v = fmaf(a4.z, fmaf(m2, inv, a2), v);
    v = fmaf(a4.w, fmaf(m3, inv, a3), v);
  }

  __shared__ float red[16];
  __shared__ float bc[2];
  float sum = v;
#pragma unroll
  for (int o = 32; o > 0; o >>= 1) sum += __shfl_down(sum, o);
  if ((t & 63) == 0) red[t >> 6] = sum;
  __syncthreads();
  if (t == 0) {
    float tot = 0;
#pragma unroll
    for (int i = 0; i < 16; ++i) tot += red[i];
    bc[0] = tot * (1.0f / 1024.0f);
  }
  __syncthreads();
  const float mean = bc[0];
  const float xc = v - mean;
  float sq = xc * xc;
  __syncthreads();
#pragma unroll
  for (int o = 32; o > 0; o >>= 1) sq += __shfl_down(sq, o);
  if ((t & 63) == 0) red[t >> 6] = sq;
  __syncthreads();
  if (t == 0) {
    float tot = 0;
#pragma unroll
    for (int i = 0; i < 16; ++i) tot += red[i];
    bc[1] = 1.0f / (sqrtf(tot * (1.0f / 1024.0f)) + EPSF);
  }
  __syncthreads();
  out[t] = xc * bc[1] * w4[c] + b4[c];
}

extern "C" void kernel_launch(void* const* d_in, const int* in_sizes, int n_in,
                              void* d_out, int out_size, void* d_ws,
                              size_t ws_size, hipStream_t stream) {
  const float* x = (const float*)d_in[0];
  const int* ei = (const int*)d_in[1];
  const float* eattr = (const float*)d_in[2];
  const int* batch = (const int*)d_in[3];
  const float* Wf = (const float*)d_in[4];
  const float* bf = (const float*)d_in[5];
  const float* Ws = (const float*)d_in[6];
  const float* bs = (const float*)d_in[7];
  const float* bn_w = (const float*)d_in[8];
  const float* bn_b = (const float*)d_in[9];
  const float* ln_w = (const float*)d_in[10];
  const float* ln_b = (const float*)d_in[11];
  const float* Wl = (const float*)d_in[12];
  const float* bl = (const float*)d_in[13];
  const float* w4 = (const float*)d_in[14];
  const float* b4 = (const float*)d_in[15];

  const int N = in_sizes[0] / 64;
  const int E = in_sizes[2] / 32;
  const int G = 512;
  const int NB = (N + 255) / 256;
  const int T16 = (E + 15) / 16;
  const int NCV = (N * 8 + 255) / 256;
  const int NH = (E + 255) / 256;

  // Workspace layout (floats; each chunk multiple of 4 => 16B alignment).
  float* ws = (float*)d_ws;
  float* agg = ws;                                   // N*64  [zeroed]
  float* stats = agg + (size_t)N * 64;               // 320   [zeroed]
  float* add_pool = stats + 320;                     // G*64  [zeroed]
  float* counts = add_pool + (size_t)G * 64;         // G     [zeroed]
  int* deg = (int*)(counts + G);                     // N     [zeroed]
  int* cursor = deg + N;                             // N
  int* bsum = cursor + N;                            // 256
  int* bpre = bsum + 256;                            // 256
  unsigned short* Bfrag = (unsigned short*)(bpre + 256);   // 20480 ush (40KB)
  unsigned short* xbf = Bfrag + 20480;                     // N*64 ush
  int2* epk = (int2*)(xbf + (size_t)N * 64);               // T16*16 int2

  size_t zeroFloats = (size_t)N * 64 + 320 + (size_t)G * 64 + G + N;
  hipMemsetAsync(agg, 0, zeroFloats * sizeof(float), stream);
  const int padE = T16 * 16 - E;
  if (padE > 0) hipMemsetAsync(epk + E, 0xFF, (size_t)padE * 8, stream);

  prep_kernel<<<NCV + 10 + NH, 256, 0, stream>>>(x, Wf, Ws, ei, xbf, Bfrag,
                                                 deg, NCV, N * 8, E);
  scan_a<<<NB, 256, 0, stream>>>(deg, bsum, N);
  scan_b<<<1, 256, 0, stream>>>(bsum, bpre, NB);
  scan_c<<<NB, 256, 0, stream>>>(deg, bpre, cursor, N);
  scatter_kernel<<<NH, 256, 0, stream>>>(ei, cursor, epk, E);
  edge_fused<<<512, 256, 0, stream>>>(epk, eattr, xbf, Bfrag, bf, bs, agg, T16,
                                      N, E);
  stats_kernel<<<512, 256, 0, stream>>>(agg, x, stats, N);
  const int chunk = (N + 511) / 512;
  node_finish<<<512, 256, 0, stream>>>(stats, bn_w, bn_b, agg, x, batch, ln_w,
                                       ln_b, add_pool, counts, N, chunk);
  graph_out<<<1, 1024, 0, stream>>>(add_pool, counts, Wl, bl, w4, b4,
                                    (float*)d_out, G);
}